// Round 4
// baseline (2332.030 us; speedup 1.0000x reference)
//
#include <hip/hip_runtime.h>
#include <hip/hip_bf16.h>

#define B_  128
#define T_  512
#define HID 512     // H = I = 512
#define NG  1536    // 3H
#define CSTRIDE 16  // sync-slot padding: 16 uints = 64B

// ---- sync buffer layout (uints) ----
// gcnt(t)  : slow-mode device step counter            [t*CSTRIDE]
// flag     : fast-mode monotonic per-(xcd,kc) counter [FLAG0 + (xcd*16+kc)*CSTRIDE]
//            producer of (xcd,kc) stores t+1 after step t's h is drained to L2;
//            consumer at step t polls >= t.  Monotonic, no reset.
// mem(x)   : XCD membership count                     [MEM0 + x*CSTRIDE]
// init     : one-time registration barrier            [INIT0]
#define GCNT(t)  ((t)*CSTRIDE)
#define FLAG0    (T_*CSTRIDE)
#define MEM0     (FLAG0 + 256*CSTRIDE)
#define INIT0    (MEM0 + 8*CSTRIDE)
#define SYNC_U32 (INIT0 + CSTRIDE)

#define NWG      128   // 16 WGs per XCD
#define NWG_XCD  16

typedef __attribute__((ext_vector_type(8))) short bf16x8;
typedef __attribute__((ext_vector_type(4))) float f32x4;
typedef unsigned int uint;
typedef unsigned short u16;

// h buffer layout (u16): 2 parities x [128 rows][1024] where
// row = batch, cols 0..511 = hi bf16, cols 512..1023 = lo bf16.
#define HROW 1024
#define HPAR 131072   // 128*1024 shorts per parity

__device__ __forceinline__ float bf2f(unsigned short h) {
  union { unsigned u; float f; } c; c.u = ((unsigned)h) << 16; return c.f;
}
__device__ __forceinline__ unsigned short f2bf_rn(float f) {
  union { float f; unsigned u; } c; c.f = f;
  return (unsigned short)((c.u + 0x7FFFu + ((c.u >> 16) & 1u)) >> 16);
}
// split fp32 -> hi (truncated bf16) + lo (rn bf16 of residual); hi+lo ~ fp32
__device__ __forceinline__ void split1(float f, short& hi, short& lo) {
  union { float f; unsigned u; } c; c.f = f;
  unsigned short h = (unsigned short)(c.u >> 16);
  float r = f - bf2f(h);
  hi = (short)h; lo = (short)f2bf_rn(r);
}
__device__ __forceinline__ void split8(float4 a, float4 b, bf16x8& hi, bf16x8& lo) {
  float v[8] = {a.x,a.y,a.z,a.w,b.x,b.y,b.z,b.w};
  #pragma unroll
  for (int i = 0; i < 8; ++i) { short h,l; split1(v[i],h,l); hi[i]=h; lo[i]=l; }
}

__device__ __forceinline__ uint aload_rlx(const uint* p) {
  return __hip_atomic_load(p, __ATOMIC_RELAXED, __HIP_MEMORY_SCOPE_AGENT);
}

// ---------------------------------------------------------------------------
// Kernel 0: split h0 (fp32) into parity-1 hi/lo buffer
// ---------------------------------------------------------------------------
__global__ void h0_pack(const float* __restrict__ h0, u16* __restrict__ hbuf) {
  int i = blockIdx.x * 256 + threadIdx.x;        // 65536 threads
  short hi, lo; split1(h0[i], hi, lo);
  u16* p = hbuf + HPAR + (i >> 9) * HROW + (i & 511);
  p[0]   = (u16)hi;
  p[512] = (u16)lo;
}

// ---------------------------------------------------------------------------
// Kernel 1: x_lin[m][n] = sum_k x[m][k]*Wx[n][k] + bx[n]
// M=65536, N=1536, K=512.  WG = 128x128 tile (2x2 waves of 64x64).
// ---------------------------------------------------------------------------
template<bool WSF32>
__global__ __launch_bounds__(256) void xlin_kernel(const float* __restrict__ x,
                                                   const float* __restrict__ Wx,
                                                   const float* __restrict__ bx,
                                                   void* __restrict__ xlin) {
  const int lane = threadIdx.x & 63;
  const int w    = threadIdx.x >> 6;
  const int wm   = w & 1, wn = w >> 1;
  const int quad = lane >> 4, l16 = lane & 15;
  const long m0  = (long)blockIdx.y * 128;
  const int  n0  = blockIdx.x * 128;

  f32x4 acc[4][4];
  #pragma unroll
  for (int i = 0; i < 4; ++i)
    #pragma unroll
    for (int j = 0; j < 4; ++j) acc[i][j] = (f32x4){0.f,0.f,0.f,0.f};

  for (int kk = 0; kk < 16; ++kk) {
    const int kq = kk*32 + quad*8;
    bf16x8 ahi[4], alo[4], bhi[4], blo[4];
    #pragma unroll
    for (int i = 0; i < 4; ++i) {
      const float* p = x + (m0 + wm*64 + i*16 + l16) * HID + kq;
      float4 f0 = ((const float4*)p)[0], f1 = ((const float4*)p)[1];
      split8(f0, f1, ahi[i], alo[i]);
      const float* q = Wx + (long)(n0 + wn*64 + i*16 + l16) * HID + kq;
      float4 g0 = ((const float4*)q)[0], g1 = ((const float4*)q)[1];
      split8(g0, g1, bhi[i], blo[i]);
    }
    #pragma unroll
    for (int i = 0; i < 4; ++i)
      #pragma unroll
      for (int j = 0; j < 4; ++j) {
        acc[i][j] = __builtin_amdgcn_mfma_f32_16x16x32_bf16(ahi[i], bhi[j], acc[i][j], 0, 0, 0);
        acc[i][j] = __builtin_amdgcn_mfma_f32_16x16x32_bf16(ahi[i], blo[j], acc[i][j], 0, 0, 0);
        acc[i][j] = __builtin_amdgcn_mfma_f32_16x16x32_bf16(alo[i], bhi[j], acc[i][j], 0, 0, 0);
      }
  }
  #pragma unroll
  for (int i = 0; i < 4; ++i) {
    #pragma unroll
    for (int j = 0; j < 4; ++j) {
      const int n = n0 + wn*64 + j*16 + l16;
      const float bias = bx[n];
      #pragma unroll
      for (int r = 0; r < 4; ++r) {
        const long m = m0 + wm*64 + i*16 + quad*4 + r;
        const float v = acc[i][j][r] + bias;
        if (WSF32) ((float*)xlin)[m * NG + n] = v;
        else       ((unsigned short*)xlin)[m * NG + n] = f2bf_rn(v);
      }
    }
  }
}

// ---------------------------------------------------------------------------
// Kernel 2: persistent GRU recurrence, XCD-local batch groups.
//
// Round-4 change: 16 WGs/XCD (128 total), each owning 32 neurons x 16
// batches.  Rationale (post-mortem of rounds 1-3): the per-step cost is
// the XCD-local rendezvous + L2 contention, all of which scale with the
// number of participants:
//   - h broadcast reads: NWG_XCD * 32KB/step of the SAME data  (1MB -> 512KB)
//   - poll sweep: NWG_XCD WGs x 4 waves x NWG_XCD lines        (4096 -> 1024)
//   - rendezvous tail: max over NWG_XCD producers              (32 -> 16)
// Compute per wave doubles (36 -> 72 MFMA ~ 360cy), still << rendezvous.
// Fast-path poll spins without s_sleep (load latency self-throttles; sleep
// quantizes wake by ~64cy on a serial chain x512).
// ---------------------------------------------------------------------------
template<bool WSF32>
__global__ __launch_bounds__(256, 1) void gru_rec(const void* __restrict__ xlin,
                                                  const float* __restrict__ Wh,
                                                  u16* __restrict__ hbuf,
                                                  uint* __restrict__ sync,
                                                  float* __restrict__ out) {
  __shared__ float red[3][4][16][34];   // [gate][wave][b][2x16 cols] pad->34:
                                        // write stagger 4*34%32=8 (2-way, free)
  __shared__ int sh_xcd, sh_cb, sh_kc;
  __shared__ uint sh_fast;
  const int tid  = threadIdx.x;
  const int lane = tid & 63;
  const int w    = tid >> 6;
  const int quad = lane >> 4, l16 = lane & 15;

  // ---- one-time: XCD discovery + balanced check ----
  if (tid == 0) {
    uint id;
    __asm__ volatile("s_getreg_b32 %0, hwreg(HW_REG_XCC_ID, 0, 32)" : "=s"(id));
    const int xcd = (int)(id & 7u);
    uint xr = __hip_atomic_fetch_add(&sync[MEM0 + xcd*CSTRIDE], 1u,
                                     __ATOMIC_RELAXED, __HIP_MEMORY_SCOPE_AGENT);
    uint* ic = &sync[INIT0];
    uint gr = __hip_atomic_fetch_add(ic, 1u, __ATOMIC_ACQ_REL, __HIP_MEMORY_SCOPE_AGENT);
    while (aload_rlx(ic) < (uint)NWG) __builtin_amdgcn_s_sleep(1);
    (void)__hip_atomic_load(ic, __ATOMIC_ACQUIRE, __HIP_MEMORY_SCOPE_AGENT);
    bool bal = true;
    #pragma unroll
    for (int x = 0; x < 8; ++x)
      bal = bal && (aload_rlx(&sync[MEM0 + x*CSTRIDE]) == (uint)NWG_XCD);
    sh_xcd  = xcd;
    sh_fast = bal ? 1u : 0u;
    sh_cb   = bal ? xcd     : (int)(gr >> 4);   // batch group (0..7)
    sh_kc   = bal ? (int)xr : (int)(gr & 15u);  // neuron slice (0..15, x32)
  }
  __syncthreads();
  const int  xcd   = sh_xcd;
  const bool fastm = (sh_fast != 0u);
  const int  cb    = sh_cb;
  const int  kc    = sh_kc;

  // ---- Wh fragments resident (split-bf16, 3-term), 2 col-tiles ----
  bf16x8 Bhi[3][2][4], Blo[3][2][4];
  #pragma unroll
  for (int g = 0; g < 3; ++g)
    #pragma unroll
    for (int c = 0; c < 2; ++c)
      #pragma unroll
      for (int kk = 0; kk < 4; ++kk) {
        const float* p = Wh + (long)(g*HID + kc*32 + c*16 + l16) * HID + w*128 + kk*32 + quad*8;
        float4 f0 = ((const float4*)p)[0], f1 = ((const float4*)p)[1];
        split8(f0, f1, Bhi[g][c][kk], Blo[g][c][kk]);
      }

  const int bb    = tid >> 4;           // 0..15 local batch (gates phase)
  const int kk2   = tid & 15;           // 0..15 within col-tile (gates phase)
  const int brow  = cb*16 + bb;         // global batch
  const int ncol0 = kc*32 + kk2;        // global neuron 0 (neuron 1 = +16)
  float* yout = out;
  float* hfin = out + (long)B_ * T_ * HID;

  // per-lane fragment base offset (shorts), parity added per step
  const int fragoff = (cb*16 + l16)*HROW + w*128 + quad*8;
  const int hpoff   = brow*HROW + ncol0;

  float xq[8][6];   // 8-step xlin register queue (2 neurons x 3 gates)
  float yq[8][2];   // 8-step y output queue

  // preload block 0
  {
    const long base = (long)brow * T_;
    #pragma unroll
    for (int q = 0; q < 8; ++q) {
      if (WSF32) {
        const float* xp = (const float*)xlin + (base + q) * NG + ncol0;
        xq[q][0] = xp[0];  xq[q][1] = xp[HID];    xq[q][2] = xp[2*HID];
        xq[q][3] = xp[16]; xq[q][4] = xp[HID+16]; xq[q][5] = xp[2*HID+16];
      } else {
        const unsigned short* xp = (const unsigned short*)xlin + (base + q) * NG + ncol0;
        xq[q][0] = bf2f(xp[0]);  xq[q][1] = bf2f(xp[HID]);    xq[q][2] = bf2f(xp[2*HID]);
        xq[q][3] = bf2f(xp[16]); xq[q][4] = bf2f(xp[HID+16]); xq[q][5] = bf2f(xp[2*HID+16]);
      }
    }
  }

  for (int tb = 0; tb < T_/8; ++tb) {
    #pragma unroll
    for (int ts = 0; ts < 8; ++ts) {
      const int t = tb*8 + ts;

      // --- consume-side wait for step t-1 ---
      if (t > 0) {
        if (fastm) {
          // 16 XCD-local flag lines; pure load-spin (self-throttled ~200cy)
          const uint* fp = &sync[FLAG0 + (xcd*16 + (lane & 15))*CSTRIDE];
          while (!__all(aload_rlx(fp) >= (uint)t)) { }
        } else {
          if (tid == 0) {
            uint* gp = &sync[GCNT(t-1)];
            while (aload_rlx(gp) < (uint)NWG) __builtin_amdgcn_s_sleep(1);
            (void)__hip_atomic_load(gp, __ATOMIC_ACQUIRE, __HIP_MEMORY_SCOPE_AGENT);
          }
          __syncthreads();
        }
      }

      const u16* rb = hbuf + ((t + 1) & 1) * HPAR;
      u16*       wb = hbuf + (t & 1)       * HPAR;

      // --- h loads: sc0 (L1-bypass) -> fresh from XCD-local L2.
      // hi fragments at +0, lo fragments at +1024B; own prev-h (2 neurons).
      const u16* hp_ = rb + fragoff;
      const u16* hpp = rb + hpoff;
      uint4 u0,u1,u2,u3,u4,u5,u6,u7; uint hu0, hu1, lu0, lu1;
      asm volatile(
        "global_load_dwordx4 %0, %12, off sc0\n\t"
        "global_load_dwordx4 %1, %12, off offset:64 sc0\n\t"
        "global_load_dwordx4 %2, %12, off offset:128 sc0\n\t"
        "global_load_dwordx4 %3, %12, off offset:192 sc0\n\t"
        "global_load_dwordx4 %4, %12, off offset:1024 sc0\n\t"
        "global_load_dwordx4 %5, %12, off offset:1088 sc0\n\t"
        "global_load_dwordx4 %6, %12, off offset:1152 sc0\n\t"
        "global_load_dwordx4 %7, %12, off offset:1216 sc0\n\t"
        "global_load_ushort %8, %13, off sc0\n\t"
        "global_load_ushort %9, %13, off offset:32 sc0\n\t"
        "global_load_ushort %10, %13, off offset:1024 sc0\n\t"
        "global_load_ushort %11, %13, off offset:1056 sc0\n\t"
        "s_waitcnt vmcnt(0)"
        : "=&v"(u0), "=&v"(u1), "=&v"(u2), "=&v"(u3),
          "=&v"(u4), "=&v"(u5), "=&v"(u6), "=&v"(u7),
          "=&v"(hu0), "=&v"(hu1), "=&v"(lu0), "=&v"(lu1)
        : "v"(hp_), "v"(hpp)
        : "memory");

      // --- GEMM: wave covers K-slice [w*128, w*128+128), 2 col-tiles ---
      f32x4 acc[3][2];
      #pragma unroll
      for (int g = 0; g < 3; ++g)
        #pragma unroll
        for (int c = 0; c < 2; ++c) acc[g][c] = (f32x4){0,0,0,0};
      {
        const bf16x8 AH[4] = { *(const bf16x8*)&u0, *(const bf16x8*)&u1,
                               *(const bf16x8*)&u2, *(const bf16x8*)&u3 };
        const bf16x8 AL[4] = { *(const bf16x8*)&u4, *(const bf16x8*)&u5,
                               *(const bf16x8*)&u6, *(const bf16x8*)&u7 };
        #pragma unroll
        for (int kk = 0; kk < 4; ++kk) {
          #pragma unroll
          for (int g = 0; g < 3; ++g) {
            #pragma unroll
            for (int c = 0; c < 2; ++c) {
              acc[g][c] = __builtin_amdgcn_mfma_f32_16x16x32_bf16(AH[kk], Bhi[g][c][kk], acc[g][c], 0, 0, 0);
              acc[g][c] = __builtin_amdgcn_mfma_f32_16x16x32_bf16(AH[kk], Blo[g][c][kk], acc[g][c], 0, 0, 0);
              acc[g][c] = __builtin_amdgcn_mfma_f32_16x16x32_bf16(AL[kk], Bhi[g][c][kk], acc[g][c], 0, 0, 0);
            }
          }
        }
      }
      #pragma unroll
      for (int g = 0; g < 3; ++g)
        #pragma unroll
        for (int c = 0; c < 2; ++c)
          #pragma unroll
          for (int r = 0; r < 4; ++r)
            red[g][w][quad*4 + r][c*16 + l16] = acc[g][c][r];

      const float hp0 = bf2f((unsigned short)hu0) + bf2f((unsigned short)lu0);
      const float hp1 = bf2f((unsigned short)hu1) + bf2f((unsigned short)lu1);

      __syncthreads();

      float az0=0.f, ar0=0.f, an0=0.f, az1=0.f, ar1=0.f, an1=0.f;
      #pragma unroll
      for (int ww = 0; ww < 4; ++ww) {
        az0 += red[0][ww][bb][kk2];      az1 += red[0][ww][bb][16+kk2];
        ar0 += red[1][ww][bb][kk2];      ar1 += red[1][ww][bb][16+kk2];
        an0 += red[2][ww][bb][kk2];      an1 += red[2][ww][bb][16+kk2];
      }
      const float z0 = 1.f / (1.f + __expf(-(az0 + xq[ts][0])));
      const float r0 = 1.f / (1.f + __expf(-(ar0 + xq[ts][1])));
      const float p0 = xq[ts][2] + r0 * an0;
      const float n0 = 2.f / (1.f + __expf(-2.f * p0)) - 1.f;   // tanh, inf-safe
      const float hn0 = (1.f - z0) * n0 + z0 * hp0;
      const float z1 = 1.f / (1.f + __expf(-(az1 + xq[ts][3])));
      const float r1 = 1.f / (1.f + __expf(-(ar1 + xq[ts][4])));
      const float p1 = xq[ts][5] + r1 * an1;
      const float n1 = 2.f / (1.f + __expf(-2.f * p1)) - 1.f;
      const float hn1 = (1.f - z1) * n1 + z1 * hp1;
      yq[ts][0] = hn0; yq[ts][1] = hn1;

      if (t < T_ - 1) {
        short h0h,h0l,h1h,h1l; split1(hn0,h0h,h0l); split1(hn1,h1h,h1l);
        u16* wp = wb + hpoff;
        wp[0]   = (u16)h0h;  wp[16]  = (u16)h1h;   // plain store -> own L2
        wp[512] = (u16)h0l;  wp[528] = (u16)h1l;
      } else {
        hfin[brow*HID + ncol0]      = hn0;
        hfin[brow*HID + ncol0 + 16] = hn1;
      }

      // __syncthreads drains every wave's h stores into L2 BEFORE the flag
      __syncthreads();
      if (t < T_ - 1) {
        if (fastm) {
          if (tid == 0)
            sync[FLAG0 + (xcd*16 + kc)*CSTRIDE] = (uint)(t + 1);  // local-L2 flag
        } else {
          if (tid == 0)
            __hip_atomic_fetch_add(&sync[GCNT(t)], 1u,
                                   __ATOMIC_RELEASE, __HIP_MEMORY_SCOPE_AGENT);
        }
      }

      // --- block boundary: flush y queue, preload next xlin block.
      // These HBM ops drain at the NEXT block's first poll (1x per 8 steps).
      if (ts == 7) {
        #pragma unroll
        for (int q = 0; q < 8; ++q) {
          float* yp = &yout[((long)brow * T_ + tb*8 + q) * HID + ncol0];
          __builtin_nontemporal_store(yq[q][0], yp);
          __builtin_nontemporal_store(yq[q][1], yp + 16);
        }
        if (tb + 1 < T_/8) {
          const long base = (long)brow * T_ + (tb + 1)*8;
          #pragma unroll
          for (int q = 0; q < 8; ++q) {
            if (WSF32) {
              const float* xp = (const float*)xlin + (base + q) * NG + ncol0;
              xq[q][0] = xp[0];  xq[q][1] = xp[HID];    xq[q][2] = xp[2*HID];
              xq[q][3] = xp[16]; xq[q][4] = xp[HID+16]; xq[q][5] = xp[2*HID+16];
            } else {
              const unsigned short* xp = (const unsigned short*)xlin + (base + q) * NG + ncol0;
              xq[q][0] = bf2f(xp[0]);  xq[q][1] = bf2f(xp[HID]);    xq[q][2] = bf2f(xp[2*HID]);
              xq[q][3] = bf2f(xp[16]); xq[q][4] = bf2f(xp[HID+16]); xq[q][5] = bf2f(xp[2*HID+16]);
            }
          }
        }
      }
    }
  }
}

// ---------------------------------------------------------------------------
extern "C" void kernel_launch(void* const* d_in, const int* in_sizes, int n_in,
                              void* d_out, int out_size, void* d_ws, size_t ws_size,
                              hipStream_t stream) {
  const float* x  = (const float*)d_in[0];
  const float* h0 = (const float*)d_in[1];
  const float* Wx = (const float*)d_in[2];
  const float* bx = (const float*)d_in[3];
  const float* Wh = (const float*)d_in[4];
  float* out = (float*)d_out;

  const size_t xlin_f32  = (size_t)B_ * T_ * NG * 4;   // 402,653,184
  const size_t xlin_bf16 = (size_t)B_ * T_ * NG * 2;   // 201,326,592
  const size_t hbuf_sz   = (size_t)2 * HPAR * 2;       // 512 KiB (hi/lo u16)
  const size_t sync_sz   = (size_t)SYNC_U32 * 4;       // ~50 KiB

  const bool wsf32 = (ws_size >= xlin_f32 + hbuf_sz + sync_sz);
  const size_t xsz = wsf32 ? xlin_f32 : xlin_bf16;
  void* xlin = d_ws;
  u16*  hbuf = (u16*)((char*)d_ws + xsz);
  uint* sync = (uint*)((char*)d_ws + xsz + hbuf_sz);

  hipMemsetAsync(sync, 0, sync_sz, stream);
  h0_pack<<<256, 256, 0, stream>>>(h0, hbuf);
  if (wsf32) {
    xlin_kernel<true ><<<dim3(12, 512), 256, 0, stream>>>(x, Wx, bx, xlin);
    gru_rec<true >    <<<NWG, 256, 0, stream>>>(xlin, Wh, hbuf, sync, out);
  } else {
    xlin_kernel<false><<<dim3(12, 512), 256, 0, stream>>>(x, Wx, bx, xlin);
    gru_rec<false>    <<<NWG, 256, 0, stream>>>(xlin, Wh, hbuf, sync, out);
  }
}